// Round 1
// baseline (238.302 us; speedup 1.0000x reference)
//
#include <hip/hip_runtime.h>
#include <hip/hip_bf16.h>

typedef __attribute__((ext_vector_type(4))) float  f32x4;
typedef __attribute__((ext_vector_type(8))) _Float16 f16x8;
typedef __attribute__((ext_vector_type(4))) _Float16 f16x4;
typedef __attribute__((ext_vector_type(4))) float  float4v;

#define BATCH   8
#define CDIM    512
#define SLEN    1024
#define NHEADS  8
#define HDIM    64

// ---------------- helpers ----------------

__device__ __forceinline__ f32x4 mfma16x16x16f16(f16x4 a, f16x4 b, f32x4 c){
#if __has_builtin(__builtin_amdgcn_mfma_f32_16x16x16f16)
    return __builtin_amdgcn_mfma_f32_16x16x16f16(a, b, c, 0, 0, 0);
#else
    asm volatile("v_mfma_f32_16x16x16_f16 %0, %1, %2, %0"
                 : "+v"(c) : "v"(a), "v"(b));
    return c;
#endif
}

// ---------------- weight convert ----------------

__global__ void convert_f16(const float* __restrict__ in, _Float16* __restrict__ out, int n){
    int i = blockIdx.x * 256 + threadIdx.x;
    if (i < n) out[i] = (_Float16)in[i];
}

// ---------------- group norm -> xnT[b][s][c] (fp16) ----------------
// one block per (b, group); group = 64 channels x 1024 spatial

__global__ __launch_bounds__(256) void gn_kernel(
    const float* __restrict__ x, const float* __restrict__ gamma,
    const float* __restrict__ beta, _Float16* __restrict__ xnT)
{
    int blk = blockIdx.x;
    int b = blk >> 3, g = blk & 7;
    const float* xp = x + ((size_t)b * CDIM + g * 64) * SLEN;

    float sum = 0.f, sq = 0.f;
    const float4v* xp4 = (const float4v*)xp;
    for (int i = threadIdx.x; i < (64 * SLEN) / 4; i += 256){
        float4v v = xp4[i];
        sum += v[0] + v[1] + v[2] + v[3];
        sq  += v[0]*v[0] + v[1]*v[1] + v[2]*v[2] + v[3]*v[3];
    }
    __shared__ float s1[256], s2[256];
    s1[threadIdx.x] = sum; s2[threadIdx.x] = sq;
    __syncthreads();
    for (int o = 128; o > 0; o >>= 1){
        if (threadIdx.x < o){ s1[threadIdx.x] += s1[threadIdx.x + o];
                              s2[threadIdx.x] += s2[threadIdx.x + o]; }
        __syncthreads();
    }
    float mean = s1[0] * (1.f / 65536.f);
    float var  = s2[0] * (1.f / 65536.f) - mean * mean;
    float inv  = rsqrtf(var + 1e-5f);

    int c  = threadIdx.x & 63;   // channel within group
    int so = threadIdx.x >> 6;   // spatial phase
    float ga = gamma[g * 64 + c] * inv;
    float be = beta[g * 64 + c] - mean * ga;
    const float* ip = xp + (size_t)c * SLEN;
    _Float16* op = xnT + (size_t)b * SLEN * CDIM + g * 64 + c;
    for (int s = so; s < SLEN; s += 4){
        op[(size_t)s * CDIM] = (_Float16)(ip[s] * ga + be);
    }
}

// ---------------- QKV GEMM: qkv[o][s] = sum_c w[o][c]*xn[c][s] ----------------
// A = w[o][c] row-major fp16, B = xnT[s][c] fp16 (B-frag reads contiguous c)
// block = 4 waves -> 128x128 tile, wave -> 64x64 (4x4 fragments)
// stores: o -> (part p, head h, d);  q,k -> [b,h,s,d];  v -> [b,h,d,s]

__global__ __launch_bounds__(256) void qkv_gemm(
    const _Float16* __restrict__ wq, const _Float16* __restrict__ xnT,
    const float* __restrict__ qkvb,
    _Float16* __restrict__ qT, _Float16* __restrict__ kT, _Float16* __restrict__ vv)
{
    int b  = blockIdx.z;
    int bo = blockIdx.y * 128, bs = blockIdx.x * 128;
    int tid = threadIdx.x;
    int wid = tid >> 6, lane = tid & 63;
    int w0 = wid >> 1, w1 = wid & 1;
    int obase = bo + w0 * 64, sbase = bs + w1 * 64;
    int lr = lane & 15, lg = lane >> 4;

    const _Float16* ap = wq  + (size_t)(obase + lr) * CDIM + lg * 8;
    const _Float16* bp = xnT + ((size_t)b * SLEN + (sbase + lr)) * CDIM + lg * 8;

    f32x4 acc[4][4];
#pragma unroll
    for (int i = 0; i < 4; i++)
#pragma unroll
        for (int j = 0; j < 4; j++) acc[i][j] = (f32x4){0.f, 0.f, 0.f, 0.f};

    for (int ks = 0; ks < CDIM; ks += 32){
        f16x8 af[4], bfr[4];
#pragma unroll
        for (int t = 0; t < 4; t++){
            af[t]  = *(const f16x8*)(ap + (size_t)t * 16 * CDIM + ks);
            bfr[t] = *(const f16x8*)(bp + (size_t)t * 16 * CDIM + ks);
        }
#pragma unroll
        for (int i = 0; i < 4; i++)
#pragma unroll
            for (int j = 0; j < 4; j++)
                acc[i][j] = __builtin_amdgcn_mfma_f32_16x16x32_f16(af[i], bfr[j], acc[i][j], 0, 0, 0);
    }

    int p = obase >> 9;            // 0=q 1=k 2=v (64-aligned range never straddles)
    int h = (obase >> 6) & 7;
    size_t bh = (size_t)b * NHEADS + h;

#pragma unroll
    for (int i = 0; i < 4; i++){
        int d0 = i * 16 + lg * 4;                     // d within head (= o & 63)
        float4v bias = *(const float4v*)(qkvb + obase + d0);
#pragma unroll
        for (int j = 0; j < 4; j++){
            int s = sbase + j * 16 + lr;
            float v0 = acc[i][j][0] + bias[0];
            float v1 = acc[i][j][1] + bias[1];
            float v2 = acc[i][j][2] + bias[2];
            float v3 = acc[i][j][3] + bias[3];
            if (p == 2){
                _Float16* vp = vv + (bh * HDIM) * SLEN + s;
                vp[(size_t)(d0 + 0) * SLEN] = (_Float16)v0;
                vp[(size_t)(d0 + 1) * SLEN] = (_Float16)v1;
                vp[(size_t)(d0 + 2) * SLEN] = (_Float16)v2;
                vp[(size_t)(d0 + 3) * SLEN] = (_Float16)v3;
            } else {
                _Float16* dst = (p == 0 ? qT : kT) + (bh * SLEN + s) * HDIM + d0;
                f16x4 pk = { (_Float16)v0, (_Float16)v1, (_Float16)v2, (_Float16)v3 };
                *(f16x4*)dst = pk;
            }
        }
    }
}

// ---------------- attention ----------------
// swapped QK^T: S^T[t][s] = mfma(A=kT, B=qT) so P^T fragment IS the B-operand
// of mfma_f32_16x16x16_f16 for PV.  O^T[d][s] accumulates, written to outT[b][s][c].
// wave: 32 s-rows (2 col-tiles), iterates t in tiles of 16. block = 4 waves = 128 s.

__global__ __launch_bounds__(256) void attn_kernel(
    const _Float16* __restrict__ qT, const _Float16* __restrict__ kT,
    const _Float16* __restrict__ vv, _Float16* __restrict__ outT)
{
    int b = blockIdx.z, h = blockIdx.y;
    size_t bh = (size_t)b * NHEADS + h;
    int tid = threadIdx.x;
    int wid = tid >> 6, lane = tid & 63;
    int lr = lane & 15, lg = lane >> 4;
    int s0 = blockIdx.x * 128 + wid * 32;

    const _Float16* qp = qT + bh * SLEN * HDIM;
    const _Float16* kp = kT + bh * SLEN * HDIM;
    const _Float16* vp = vv + bh * HDIM * SLEN;

    f16x8 qf[2][2];
#pragma unroll
    for (int sj = 0; sj < 2; sj++)
#pragma unroll
        for (int kk = 0; kk < 2; kk++)
            qf[sj][kk] = *(const f16x8*)(qp + (size_t)(s0 + sj * 16 + lr) * HDIM + kk * 32 + lg * 8);

    float m[2] = {-1e30f, -1e30f}, lsum[2] = {0.f, 0.f};
    f32x4 oac[4][2];
#pragma unroll
    for (int i = 0; i < 4; i++){
        oac[i][0] = (f32x4){0.f, 0.f, 0.f, 0.f};
        oac[i][1] = (f32x4){0.f, 0.f, 0.f, 0.f};
    }

    for (int t0 = 0; t0 < SLEN; t0 += 16){
        f16x8 kf[2];
#pragma unroll
        for (int kk = 0; kk < 2; kk++)
            kf[kk] = *(const f16x8*)(kp + (size_t)(t0 + lr) * HDIM + kk * 32 + lg * 8);
        f16x4 vf[4];
#pragma unroll
        for (int dt = 0; dt < 4; dt++)
            vf[dt] = *(const f16x4*)(vp + (size_t)(dt * 16 + lr) * SLEN + t0 + lg * 4);

#pragma unroll
        for (int sj = 0; sj < 2; sj++){
            f32x4 st = (f32x4){0.f, 0.f, 0.f, 0.f};
            st = __builtin_amdgcn_mfma_f32_16x16x32_f16(kf[0], qf[sj][0], st, 0, 0, 0);
            st = __builtin_amdgcn_mfma_f32_16x16x32_f16(kf[1], qf[sj][1], st, 0, 0, 0);
            // st[r] = logits^T[t0 + lg*4 + r][s0 + sj*16 + lr] (unscaled)
            float p0 = st[0] * 0.125f, p1 = st[1] * 0.125f;
            float p2 = st[2] * 0.125f, p3 = st[3] * 0.125f;
            float tm = fmaxf(fmaxf(p0, p1), fmaxf(p2, p3));
            tm = fmaxf(tm, __shfl_xor(tm, 16));
            tm = fmaxf(tm, __shfl_xor(tm, 32));
            float mnew = fmaxf(m[sj], tm);
            float corr = __expf(m[sj] - mnew);
            m[sj] = mnew;
            p0 = __expf(p0 - mnew); p1 = __expf(p1 - mnew);
            p2 = __expf(p2 - mnew); p3 = __expf(p3 - mnew);
            float ts = p0 + p1 + p2 + p3;
            ts += __shfl_xor(ts, 16);
            ts += __shfl_xor(ts, 32);
            lsum[sj] = lsum[sj] * corr + ts;
            f16x4 pb = { (_Float16)p0, (_Float16)p1, (_Float16)p2, (_Float16)p3 };
#pragma unroll
            for (int dt = 0; dt < 4; dt++){
                f32x4 o = oac[dt][sj];
                o[0] *= corr; o[1] *= corr; o[2] *= corr; o[3] *= corr;
                oac[dt][sj] = mfma16x16x16f16(vf[dt], pb, o);
            }
        }
    }

#pragma unroll
    for (int sj = 0; sj < 2; sj++){
        float inv = 1.f / lsum[sj];
        int s = s0 + sj * 16 + lr;
#pragma unroll
        for (int dt = 0; dt < 4; dt++){
            f16x4 ob = { (_Float16)(oac[dt][sj][0] * inv), (_Float16)(oac[dt][sj][1] * inv),
                         (_Float16)(oac[dt][sj][2] * inv), (_Float16)(oac[dt][sj][3] * inv) };
            *(f16x4*)(outT + ((size_t)b * SLEN + s) * CDIM + h * HDIM + dt * 16 + lg * 4) = ob;
        }
    }
}

// ---------------- proj GEMM + bias + residual ----------------

__global__ __launch_bounds__(256) void proj_gemm(
    const _Float16* __restrict__ pw, const _Float16* __restrict__ outT,
    const float* __restrict__ pb, const float* __restrict__ x,
    float* __restrict__ y)
{
    int b  = blockIdx.z;
    int bo = blockIdx.y * 128, bs = blockIdx.x * 128;
    int tid = threadIdx.x;
    int wid = tid >> 6, lane = tid & 63;
    int w0 = wid >> 1, w1 = wid & 1;
    int obase = bo + w0 * 64, sbase = bs + w1 * 64;
    int lr = lane & 15, lg = lane >> 4;

    const _Float16* ap = pw   + (size_t)(obase + lr) * CDIM + lg * 8;
    const _Float16* bp = outT + ((size_t)b * SLEN + (sbase + lr)) * CDIM + lg * 8;

    f32x4 acc[4][4];
#pragma unroll
    for (int i = 0; i < 4; i++)
#pragma unroll
        for (int j = 0; j < 4; j++) acc[i][j] = (f32x4){0.f, 0.f, 0.f, 0.f};

    for (int ks = 0; ks < CDIM; ks += 32){
        f16x8 af[4], bfr[4];
#pragma unroll
        for (int t = 0; t < 4; t++){
            af[t]  = *(const f16x8*)(ap + (size_t)t * 16 * CDIM + ks);
            bfr[t] = *(const f16x8*)(bp + (size_t)t * 16 * CDIM + ks);
        }
#pragma unroll
        for (int i = 0; i < 4; i++)
#pragma unroll
            for (int j = 0; j < 4; j++)
                acc[i][j] = __builtin_amdgcn_mfma_f32_16x16x32_f16(af[i], bfr[j], acc[i][j], 0, 0, 0);
    }

#pragma unroll
    for (int i = 0; i < 4; i++){
        int o0 = obase + i * 16 + lg * 4;
        float4v bias = *(const float4v*)(pb + o0);
#pragma unroll
        for (int j = 0; j < 4; j++){
            int s = sbase + j * 16 + lr;
#pragma unroll
            for (int r = 0; r < 4; r++){
                size_t idx = ((size_t)b * CDIM + o0 + r) * SLEN + s;
                y[idx] = acc[i][j][r] + bias[r] + x[idx];
            }
        }
    }
}

// ---------------- launcher ----------------

extern "C" void kernel_launch(void* const* d_in, const int* in_sizes, int n_in,
                              void* d_out, int out_size, void* d_ws, size_t ws_size,
                              hipStream_t stream)
{
    const float* x     = (const float*)d_in[0];
    const float* gamma = (const float*)d_in[1];
    const float* beta  = (const float*)d_in[2];
    const float* qkvw  = (const float*)d_in[3];
    const float* qkvb  = (const float*)d_in[4];
    const float* projw = (const float*)d_in[5];
    const float* projb = (const float*)d_in[6];
    float* out = (float*)d_out;

    char* ws = (char*)d_ws;
    _Float16* wq_bf = (_Float16*)(ws);                       // 1536*512*2 = 1.5 MB
    _Float16* pw_bf = (_Float16*)(ws + 1572864);             // 512*512*2  = 0.5 MB
    _Float16* xnT   = (_Float16*)(ws + 2097152);             // 8 MB  [b][s][c]
    _Float16* qT    = (_Float16*)(ws + 2097152 + 8388608);   // 8 MB  [b][h][s][d]
    _Float16* kT    = (_Float16*)(ws + 2097152 + 16777216);  // 8 MB  [b][h][s][d]
    _Float16* vv    = (_Float16*)(ws + 2097152 + 25165824);  // 8 MB  [b][h][d][s]
    _Float16* outT  = (_Float16*)(ws + 2097152 + 33554432);  // 8 MB  [b][s][c]

    convert_f16<<<(1536 * 512 + 255) / 256, 256, 0, stream>>>(qkvw, wq_bf, 1536 * 512);
    convert_f16<<<(512 * 512 + 255) / 256, 256, 0, stream>>>(projw, pw_bf, 512 * 512);
    gn_kernel<<<64, 256, 0, stream>>>(x, gamma, beta, xnT);
    qkv_gemm<<<dim3(8, 12, 8), 256, 0, stream>>>(wq_bf, xnT, qkvb, qT, kT, vv);
    attn_kernel<<<dim3(8, 8, 8), 256, 0, stream>>>(qT, kT, vv, outT);
    proj_gemm<<<dim3(8, 4, 8), 256, 0, stream>>>(pw_bf, outT, projb, x, out);
}